// Round 4
// baseline (437.482 us; speedup 1.0000x reference)
//
#include <hip/hip_runtime.h>
#include <hip/hip_bf16.h>
#include <stdint.h>

// HyperbolicAdaptiveGraph: out[i][j] = exp(-acosh(1 + 2*max(ni+nj-2*dot_ij,0)/((1-ni)^2+eps) + eps))
// row-normalized. N=8192, D=64. Output f32 [N,N] = 256 MB.
// Split-bf16 MFMA Gram (hi+lo, 3 MFMA terms -> ~f32-accurate dot), closed-form
// exp(-acosh(x)) = 1/(x+sqrt(x^2-1)), exact diagonal (num==0).
// 3 launches: prep / pass A (rowsums only, no store) / pass B (recompute +
// normalize + store). Recompute (≈22 µs MFMA) beats re-reading 512 MB (≈85 µs).

#define N 8192
#define D 64
#define EPSF 1e-8f

typedef __bf16 bf16x8 __attribute__((ext_vector_type(8)));
typedef float  f32x4  __attribute__((ext_vector_type(4)));

static __device__ __forceinline__ unsigned short f32_to_bf16_rne(float f) {
    union { float f; uint32_t u; } c; c.f = f;
    return (unsigned short)((c.u + 0x7FFFu + ((c.u >> 16) & 1u)) >> 16);
}
static __device__ __forceinline__ float bf16_bits_to_f32(unsigned short h) {
    union { uint32_t u; float f; } c; c.u = ((uint32_t)h) << 16; return c.f;
}

// ---------------- K1: f32 -> bf16 hi+lo split, row norms, zero rowsum ----------------
__global__ __launch_bounds__(256) void prep_kernel(
    const float* __restrict__ emb, unsigned short* __restrict__ eh,
    unsigned short* __restrict__ el, float* __restrict__ nrm,
    float* __restrict__ rowsum)
{
    int tid = blockIdx.x * 256 + threadIdx.x;     // 2048 blocks * 256 = 8192*64 exactly
    if (tid < N) rowsum[tid] = 0.0f;              // d_ws is re-poisoned each call
    int row = tid >> 6;
    int k   = tid & 63;
    float v = emb[(size_t)row * D + k];
    unsigned short h = f32_to_bf16_rne(v);
    float lo = v - bf16_bits_to_f32(h);
    eh[(size_t)row * D + k] = h;
    el[(size_t)row * D + k] = f32_to_bf16_rne(lo);
    float sq = v * v;
    #pragma unroll
    for (int m = 32; m; m >>= 1) sq += __shfl_xor(sq, m, 64);
    if (k == 0) nrm[row] = sq;
}

// ---------------- K2: split-bf16 Gram via MFMA + epilogue ----------------
// Block = 256 thr = 4 waves, block tile 128x128 (2x2 waves of 64x64).
// Wave tile 64x64 = 4x4 frags of 16x16, K=64 via 2 x mfma_f32_16x16x32_bf16.
// dot = hi*hi^T + hi*lo^T + lo*hi^T   (lo*lo dropped, ~2^-18 rel)
// A/B frag: lane l holds emb[base + (l&15)][(l>>4)*8 + e], e=0..7  (16B load).
// C/D frag: col = lane&15, row = (lane>>4)*4 + reg.
// STORE=false: accumulate row sums via atomics, no stores.
// STORE=true : read rowsum, write normalized adp (bitwise-identical recompute).
template <bool STORE>
__global__ __launch_bounds__(256) void gemm_epi_kernel(
    const unsigned short* __restrict__ eh, const unsigned short* __restrict__ el,
    const float* __restrict__ nrm, float* __restrict__ out,
    float* __restrict__ rowsum)
{
    const int lane = threadIdx.x & 63;
    const int wid  = threadIdx.x >> 6;
    const int bx = blockIdx.x & 63;
    const int by = blockIdx.x >> 6;
    const int brow = by * 128 + (wid >> 1) * 64;
    const int bcol = bx * 128 + (wid & 1) * 64;
    const int lr = lane & 15;
    const int lk = (lane >> 4) * 8;

    bf16x8 ah[4][2], al[4][2];
    #pragma unroll
    for (int g = 0; g < 4; ++g) {
        #pragma unroll
        for (int h = 0; h < 2; ++h) {
            size_t off = (size_t)(brow + g*16 + lr) * D + h*32 + lk;
            ah[g][h] = *reinterpret_cast<const bf16x8*>(eh + off);
            al[g][h] = *reinterpret_cast<const bf16x8*>(el + off);
        }
    }

    f32x4 acc[4][4];
    #pragma unroll
    for (int rg = 0; rg < 4; ++rg)
        #pragma unroll
        for (int cg = 0; cg < 4; ++cg)
            acc[rg][cg] = (f32x4){0.f, 0.f, 0.f, 0.f};

    #pragma unroll
    for (int cg = 0; cg < 4; ++cg) {
        bf16x8 bh[2], bl[2];
        #pragma unroll
        for (int h = 0; h < 2; ++h) {
            size_t off = (size_t)(bcol + cg*16 + lr) * D + h*32 + lk;
            bh[h] = *reinterpret_cast<const bf16x8*>(eh + off);
            bl[h] = *reinterpret_cast<const bf16x8*>(el + off);
        }
        #pragma unroll
        for (int rg = 0; rg < 4; ++rg) {
            #pragma unroll
            for (int h = 0; h < 2; ++h) {
                acc[rg][cg] = __builtin_amdgcn_mfma_f32_16x16x32_bf16(ah[rg][h], bh[h], acc[rg][cg], 0, 0, 0);
                acc[rg][cg] = __builtin_amdgcn_mfma_f32_16x16x32_bf16(ah[rg][h], bl[h], acc[rg][cg], 0, 0, 0);
                acc[rg][cg] = __builtin_amdgcn_mfma_f32_16x16x32_bf16(al[rg][h], bh[h], acc[rg][cg], 0, 0, 0);
            }
        }
    }

    // Epilogue: adp = 1/((1+t) + sqrt(t*(t+2))), t = 2*num/denom + eps
    #pragma unroll
    for (int rg = 0; rg < 4; ++rg) {
        const int ibase = brow + rg * 16 + (lane >> 4) * 4;
        float ni[4], rd[4], sc[4];
        #pragma unroll
        for (int r = 0; r < 4; ++r) {
            ni[r] = nrm[ibase + r];
            float om = 1.0f - ni[r];
            rd[r] = 1.0f / (om * om + EPSF);
            if (STORE) sc[r] = 1.0f / (rowsum[ibase + r] + EPSF);
        }
        float rs[4] = {0.f, 0.f, 0.f, 0.f};
        #pragma unroll
        for (int cg = 0; cg < 4; ++cg) {
            const int j = bcol + cg * 16 + lr;
            const float nj = nrm[j];
            #pragma unroll
            for (int r = 0; r < 4; ++r) {
                float num = fmaxf(ni[r] + nj - 2.0f * acc[rg][cg][r], 0.0f);
                if (ibase + r == j) num = 0.0f;   // exact diagonal: t -> EPS
                float t = 2.0f * num * rd[r] + EPSF;
                float adp = 1.0f / ((1.0f + t) + sqrtf(t * (t + 2.0f)));
                if (STORE) {
                    out[(size_t)(ibase + r) * N + j] = adp * sc[r];
                } else {
                    rs[r] += adp;
                }
            }
        }
        if (!STORE) {
            // reduce rs over the 16 lanes sharing this row group (low 4 lane bits)
            #pragma unroll
            for (int r = 0; r < 4; ++r) {
                float v = rs[r];
                v += __shfl_xor(v, 1, 64);
                v += __shfl_xor(v, 2, 64);
                v += __shfl_xor(v, 4, 64);
                v += __shfl_xor(v, 8, 64);
                if (lr == 0) atomicAdd(&rowsum[ibase + r], v);
            }
        }
    }
}

extern "C" void kernel_launch(void* const* d_in, const int* in_sizes, int n_in,
                              void* d_out, int out_size, void* d_ws, size_t ws_size,
                              hipStream_t stream)
{
    const float* emb = (const float*)d_in[0];
    float* out = (float*)d_out;
    char* ws = (char*)d_ws;
    unsigned short* eh = (unsigned short*)ws;                        // 1 MiB
    unsigned short* el = eh + (size_t)N * D;                         // 1 MiB
    float* nrm  = (float*)(ws + (size_t)N * D * 4);                  // 32 KiB
    float* rsum = nrm + N;                                           // 32 KiB

    hipLaunchKernelGGL(prep_kernel, dim3((N * D) / 256), dim3(256), 0, stream,
                       emb, eh, el, nrm, rsum);
    hipLaunchKernelGGL((gemm_epi_kernel<false>), dim3((N/128)*(N/128)), dim3(256), 0, stream,
                       eh, el, nrm, out, rsum);
    hipLaunchKernelGGL((gemm_epi_kernel<true>),  dim3((N/128)*(N/128)), dim3(256), 0, stream,
                       eh, el, nrm, out, rsum);
}

// Round 5
// 371.074 us; speedup vs baseline: 1.1790x; 1.1790x over previous
//
#include <hip/hip_runtime.h>
#include <hip/hip_bf16.h>
#include <stdint.h>
#include <type_traits>

// HyperbolicAdaptiveGraph: out[i][j] = exp(-acosh(1 + 2*max(ni+nj-2*dot_ij,0)/((1-ni)^2+eps) + eps))
// row-normalized. N=8192, D=64. Output f32 [N,N] = 256 MB.
// exp(-acosh(1+t)) = 1/(1+t+sqrt(t^2+2t)) exactly -> fast v_rcp/v_sqrt (1 ulp).
// Pass A: hi-only bf16 Gram -> rowsums (err ~2e-8 post-norm, no stores).
// Pass B: split-bf16 Gram (hi*hi+hi*lo+lo*hi) -> normalized store (256 MB only).

#define N 8192
#define D 64
#define EPSF 1e-8f

typedef __bf16 bf16x8 __attribute__((ext_vector_type(8)));
typedef float  f32x4  __attribute__((ext_vector_type(4)));

static __device__ __forceinline__ unsigned short f32_to_bf16_rne(float f) {
    union { float f; uint32_t u; } c; c.f = f;
    return (unsigned short)((c.u + 0x7FFFu + ((c.u >> 16) & 1u)) >> 16);
}
static __device__ __forceinline__ float bf16_bits_to_f32(unsigned short h) {
    union { uint32_t u; float f; } c; c.u = ((uint32_t)h) << 16; return c.f;
}

// ---------------- K1: f32 -> bf16 hi+lo split, row norms, zero rowsum ----------------
__global__ __launch_bounds__(256) void prep_kernel(
    const float* __restrict__ emb, unsigned short* __restrict__ eh,
    unsigned short* __restrict__ el, float* __restrict__ nrm,
    float* __restrict__ rowsum)
{
    int tid = blockIdx.x * 256 + threadIdx.x;     // 2048 blocks * 256 = 8192*64 exactly
    if (tid < N) rowsum[tid] = 0.0f;              // d_ws is re-poisoned each call
    int row = tid >> 6;
    int k   = tid & 63;
    float v = emb[(size_t)row * D + k];
    unsigned short h = f32_to_bf16_rne(v);
    float lo = v - bf16_bits_to_f32(h);
    eh[(size_t)row * D + k] = h;
    el[(size_t)row * D + k] = f32_to_bf16_rne(lo);
    float sq = v * v;
    #pragma unroll
    for (int m = 32; m; m >>= 1) sq += __shfl_xor(sq, m, 64);
    if (k == 0) nrm[row] = sq;
}

// ---------------- K2: Gram via MFMA + epilogue ----------------
// Block = 256 thr = 4 waves, block tile 128x128 (2x2 waves of 64x64).
// Wave tile 64x64 = 4x4 frags of 16x16, K=64 via 2 x mfma_f32_16x16x32_bf16.
// A/B frag: lane l holds emb[base + (l&15)][(l>>4)*8 + e], e=0..7  (16B load).
// C/D frag: col = lane&15, row = (lane>>4)*4 + reg.
// STORE=false: hi-only Gram, accumulate row sums via atomics, no stores.
// STORE=true : split Gram (3 terms), read rowsum, write normalized adp.
template <bool STORE>
__global__ __launch_bounds__(256) void gemm_epi_kernel(
    const unsigned short* __restrict__ eh, const unsigned short* __restrict__ el,
    const float* __restrict__ nrm, float* __restrict__ out,
    float* __restrict__ rowsum)
{
    const int lane = threadIdx.x & 63;
    const int wid  = threadIdx.x >> 6;
    const int bx = blockIdx.x & 63;
    const int by = blockIdx.x >> 6;
    const int brow = by * 128 + (wid >> 1) * 64;
    const int bcol = bx * 128 + (wid & 1) * 64;
    const int lr = lane & 15;
    const int lk = (lane >> 4) * 8;

    bf16x8 ah[4][2], al[4][2];
    #pragma unroll
    for (int g = 0; g < 4; ++g) {
        #pragma unroll
        for (int h = 0; h < 2; ++h) {
            size_t off = (size_t)(brow + g*16 + lr) * D + h*32 + lk;
            ah[g][h] = *reinterpret_cast<const bf16x8*>(eh + off);
            if (STORE) al[g][h] = *reinterpret_cast<const bf16x8*>(el + off);
        }
    }

    f32x4 acc[4][4];
    #pragma unroll
    for (int rg = 0; rg < 4; ++rg)
        #pragma unroll
        for (int cg = 0; cg < 4; ++cg)
            acc[rg][cg] = (f32x4){0.f, 0.f, 0.f, 0.f};

    #pragma unroll
    for (int cg = 0; cg < 4; ++cg) {
        bf16x8 bh[2], bl[2];
        #pragma unroll
        for (int h = 0; h < 2; ++h) {
            size_t off = (size_t)(bcol + cg*16 + lr) * D + h*32 + lk;
            bh[h] = *reinterpret_cast<const bf16x8*>(eh + off);
            if (STORE) bl[h] = *reinterpret_cast<const bf16x8*>(el + off);
        }
        #pragma unroll
        for (int rg = 0; rg < 4; ++rg) {
            #pragma unroll
            for (int h = 0; h < 2; ++h) {
                acc[rg][cg] = __builtin_amdgcn_mfma_f32_16x16x32_bf16(ah[rg][h], bh[h], acc[rg][cg], 0, 0, 0);
                if (STORE) {
                    acc[rg][cg] = __builtin_amdgcn_mfma_f32_16x16x32_bf16(ah[rg][h], bl[h], acc[rg][cg], 0, 0, 0);
                    acc[rg][cg] = __builtin_amdgcn_mfma_f32_16x16x32_bf16(al[rg][h], bh[h], acc[rg][cg], 0, 0, 0);
                }
            }
        }
    }

    // Epilogue: adp = rcp((1+t) + sqrt(t*t+2t)), t = num*rd2 + eps, rd2 = 2/denom.
    // Fast v_rcp/v_sqrt: ~1 ulp, values ~0.7 -> post-norm error ~1e-11. DIAG
    // (i==j -> num=0) only on diagonal blocks.
    auto epilogue = [&](auto diag_c) {
        constexpr bool DIAG = decltype(diag_c)::value;
        #pragma unroll
        for (int rg = 0; rg < 4; ++rg) {
            const int ibase = brow + rg * 16 + (lane >> 4) * 4;
            float ni[4], rd2[4], sc[4];
            #pragma unroll
            for (int r = 0; r < 4; ++r) {
                ni[r] = nrm[ibase + r];
                float om = 1.0f - ni[r];
                rd2[r] = 2.0f * __builtin_amdgcn_rcpf(om * om + EPSF);
                if (STORE) sc[r] = __builtin_amdgcn_rcpf(rowsum[ibase + r] + EPSF);
            }
            float rs[4] = {0.f, 0.f, 0.f, 0.f};
            #pragma unroll
            for (int cg = 0; cg < 4; ++cg) {
                const int j = bcol + cg * 16 + lr;
                const float nj = nrm[j];
                #pragma unroll
                for (int r = 0; r < 4; ++r) {
                    float num = fmaxf(fmaf(-2.0f, acc[rg][cg][r], ni[r] + nj), 0.0f);
                    if (DIAG) { if (ibase + r == j) num = 0.0f; }  // exact diagonal: t -> EPS
                    float t = fmaf(num, rd2[r], EPSF);
                    float s = fmaf(t, t, t + t);
                    float adp = __builtin_amdgcn_rcpf((1.0f + t) + __builtin_amdgcn_sqrtf(s));
                    if (STORE) {
                        out[(size_t)(ibase + r) * N + j] = adp * sc[r];
                    } else {
                        rs[r] += adp;
                    }
                }
            }
            if (!STORE) {
                // reduce rs over the 16 lanes sharing this row group (low 4 lane bits)
                #pragma unroll
                for (int r = 0; r < 4; ++r) {
                    float v = rs[r];
                    v += __shfl_xor(v, 1, 64);
                    v += __shfl_xor(v, 2, 64);
                    v += __shfl_xor(v, 4, 64);
                    v += __shfl_xor(v, 8, 64);
                    if (lr == 0) atomicAdd(&rowsum[ibase + r], v);
                }
            }
        }
    };
    if (bx == by) epilogue(std::true_type{});
    else          epilogue(std::false_type{});
}

extern "C" void kernel_launch(void* const* d_in, const int* in_sizes, int n_in,
                              void* d_out, int out_size, void* d_ws, size_t ws_size,
                              hipStream_t stream)
{
    const float* emb = (const float*)d_in[0];
    float* out = (float*)d_out;
    char* ws = (char*)d_ws;
    unsigned short* eh = (unsigned short*)ws;                        // 1 MiB
    unsigned short* el = eh + (size_t)N * D;                         // 1 MiB
    float* nrm  = (float*)(ws + (size_t)N * D * 4);                  // 32 KiB
    float* rsum = nrm + N;                                           // 32 KiB

    hipLaunchKernelGGL(prep_kernel, dim3((N * D) / 256), dim3(256), 0, stream,
                       emb, eh, el, nrm, rsum);
    hipLaunchKernelGGL((gemm_epi_kernel<false>), dim3((N/128)*(N/128)), dim3(256), 0, stream,
                       eh, el, nrm, out, rsum);
    hipLaunchKernelGGL((gemm_epi_kernel<true>),  dim3((N/128)*(N/128)), dim3(256), 0, stream,
                       eh, el, nrm, out, rsum);
}

// Round 6
// 355.109 us; speedup vs baseline: 1.2320x; 1.0450x over previous
//
#include <hip/hip_runtime.h>
#include <hip/hip_bf16.h>
#include <stdint.h>
#include <type_traits>

// HyperbolicAdaptiveGraph: out[i][j] = exp(-acosh(1 + 2*max(ni+nj-2*dot_ij,0)/((1-ni)^2+eps) + eps))
// row-normalized. N=8192, D=64. Output f32 [N,N] = 256 MB.
// exp(-acosh(1+t)) = 1/(1+t+sqrt(t^2+2t)) exactly -> fast v_rcp/v_sqrt (1 ulp).
// Hi-only bf16 Gram everywhere: off-diagonal t~0.065 is in the smooth region
// (adp slope ~-1.9 -> post-norm err ~3e-8); the only sqrt-amplified point is
// the diagonal, which is forced exact (num=0). Pass A: rowsums (no stores).
// Pass B: bitwise-identical recompute + normalized store (256 MB, write-bound).

#define N 8192
#define D 64
#define EPSF 1e-8f

typedef __bf16 bf16x8 __attribute__((ext_vector_type(8)));
typedef float  f32x4  __attribute__((ext_vector_type(4)));

static __device__ __forceinline__ unsigned short f32_to_bf16_rne(float f) {
    union { float f; uint32_t u; } c; c.f = f;
    return (unsigned short)((c.u + 0x7FFFu + ((c.u >> 16) & 1u)) >> 16);
}

// ---------------- K1: f32 -> bf16 (RNE), row norms, zero rowsum ----------------
__global__ __launch_bounds__(256) void prep_kernel(
    const float* __restrict__ emb, unsigned short* __restrict__ eh,
    float* __restrict__ nrm, float* __restrict__ rowsum)
{
    int tid = blockIdx.x * 256 + threadIdx.x;     // 2048 blocks * 256 = 8192*64 exactly
    if (tid < N) rowsum[tid] = 0.0f;              // d_ws is re-poisoned each call
    int row = tid >> 6;
    int k   = tid & 63;
    float v = emb[(size_t)row * D + k];
    eh[(size_t)row * D + k] = f32_to_bf16_rne(v);
    float sq = v * v;
    #pragma unroll
    for (int m = 32; m; m >>= 1) sq += __shfl_xor(sq, m, 64);
    if (k == 0) nrm[row] = sq;
}

// ---------------- K2: hi-only bf16 Gram via MFMA + fused epilogue ----------------
// Block = 256 thr = 4 waves, block tile 128x128 (2x2 waves of 64x64).
// Wave tile 64x64 = 4x4 frags of 16x16, K=64 via 2 x mfma_f32_16x16x32_bf16.
// A/B frag: lane l holds emb[base + (l&15)][(l>>4)*8 + e], e=0..7  (16B load).
// C/D frag: col = lane&15, row = (lane>>4)*4 + reg.
// Epilogue runs per (cg,rg) on a single f32x4 acc -> low VGPR, MFMA/VALU pipeline.
// STORE=false: accumulate row sums via shfl tree + one atomic per row-segment.
// STORE=true : read rowsum, write normalized adp (bitwise-identical recompute).
template <bool STORE>
__global__ __launch_bounds__(256) void gemm_epi_kernel(
    const unsigned short* __restrict__ eh, const float* __restrict__ nrm,
    float* __restrict__ out, float* __restrict__ rowsum)
{
    const int lane = threadIdx.x & 63;
    const int wid  = threadIdx.x >> 6;
    const int bx = blockIdx.x & 63;
    const int by = blockIdx.x >> 6;
    const int brow = by * 128 + (wid >> 1) * 64;
    const int bcol = bx * 128 + (wid & 1) * 64;
    const int lr = lane & 15;
    const int lk = (lane >> 4) * 8;

    bf16x8 ah[4][2];
    #pragma unroll
    for (int g = 0; g < 4; ++g)
        #pragma unroll
        for (int h = 0; h < 2; ++h)
            ah[g][h] = *reinterpret_cast<const bf16x8*>(eh + (size_t)(brow + g*16 + lr) * D + h*32 + lk);

    // Row constants per (rg, r): row index = brow + rg*16 + (lane>>4)*4 + r
    float ni[4][4], rd2[4][4], sc[4][4];
    #pragma unroll
    for (int rg = 0; rg < 4; ++rg) {
        const int ibase = brow + rg * 16 + (lane >> 4) * 4;
        #pragma unroll
        for (int r = 0; r < 4; ++r) {
            ni[rg][r] = nrm[ibase + r];
            float om = 1.0f - ni[rg][r];
            rd2[rg][r] = 2.0f * __builtin_amdgcn_rcpf(om * om + EPSF);
            if (STORE) sc[rg][r] = __builtin_amdgcn_rcpf(rowsum[ibase + r] + EPSF);
        }
    }

    float rs[4][4];
    if (!STORE)
        #pragma unroll
        for (int rg = 0; rg < 4; ++rg)
            #pragma unroll
            for (int r = 0; r < 4; ++r) rs[rg][r] = 0.0f;

    auto body = [&](auto diag_c) {
        constexpr bool DIAG = decltype(diag_c)::value;
        #pragma unroll
        for (int cg = 0; cg < 4; ++cg) {
            bf16x8 bh[2];
            #pragma unroll
            for (int h = 0; h < 2; ++h)
                bh[h] = *reinterpret_cast<const bf16x8*>(eh + (size_t)(bcol + cg*16 + lr) * D + h*32 + lk);
            const int j = bcol + cg * 16 + lr;
            const float nj = nrm[j];
            #pragma unroll
            for (int rg = 0; rg < 4; ++rg) {
                f32x4 acc = (f32x4){0.f, 0.f, 0.f, 0.f};
                acc = __builtin_amdgcn_mfma_f32_16x16x32_bf16(ah[rg][0], bh[0], acc, 0, 0, 0);
                acc = __builtin_amdgcn_mfma_f32_16x16x32_bf16(ah[rg][1], bh[1], acc, 0, 0, 0);
                const int ibase = brow + rg * 16 + (lane >> 4) * 4;
                #pragma unroll
                for (int r = 0; r < 4; ++r) {
                    float num = fmaxf(fmaf(-2.0f, acc[r], ni[rg][r] + nj), 0.0f);
                    if (DIAG) { if (ibase + r == j) num = 0.0f; }  // exact diagonal: t -> EPS
                    float t = fmaf(num, rd2[rg][r], EPSF);
                    float s = fmaf(t, t, t + t);
                    float adp = __builtin_amdgcn_rcpf((1.0f + t) + __builtin_amdgcn_sqrtf(s));
                    if (STORE) {
                        out[(size_t)(ibase + r) * N + j] = adp * sc[rg][r];
                    } else {
                        rs[rg][r] += adp;
                    }
                }
            }
        }
    };
    if (bx == by) body(std::true_type{});
    else          body(std::false_type{});

    if (!STORE) {
        // reduce rs over the 16 lanes sharing each row group (low 4 lane bits)
        #pragma unroll
        for (int rg = 0; rg < 4; ++rg) {
            const int ibase = brow + rg * 16 + (lane >> 4) * 4;
            #pragma unroll
            for (int r = 0; r < 4; ++r) {
                float v = rs[rg][r];
                v += __shfl_xor(v, 1, 64);
                v += __shfl_xor(v, 2, 64);
                v += __shfl_xor(v, 4, 64);
                v += __shfl_xor(v, 8, 64);
                if (lr == 0) atomicAdd(&rowsum[ibase + r], v);
            }
        }
    }
}

extern "C" void kernel_launch(void* const* d_in, const int* in_sizes, int n_in,
                              void* d_out, int out_size, void* d_ws, size_t ws_size,
                              hipStream_t stream)
{
    const float* emb = (const float*)d_in[0];
    float* out = (float*)d_out;
    char* ws = (char*)d_ws;
    unsigned short* eh = (unsigned short*)ws;                        // 1 MiB
    float* nrm  = (float*)(ws + (size_t)N * D * 2);                  // 32 KiB
    float* rsum = nrm + N;                                           // 32 KiB

    hipLaunchKernelGGL(prep_kernel, dim3((N * D) / 256), dim3(256), 0, stream,
                       emb, eh, nrm, rsum);
    hipLaunchKernelGGL((gemm_epi_kernel<false>), dim3((N/128)*(N/128)), dim3(256), 0, stream,
                       eh, nrm, out, rsum);
    hipLaunchKernelGGL((gemm_epi_kernel<true>),  dim3((N/128)*(N/128)), dim3(256), 0, stream,
                       eh, nrm, out, rsum);
}

// Round 7
// 348.274 us; speedup vs baseline: 1.2561x; 1.0196x over previous
//
#include <hip/hip_runtime.h>
#include <hip/hip_bf16.h>
#include <stdint.h>
#include <type_traits>

// HyperbolicAdaptiveGraph: out[i][j] = exp(-acosh(1 + 2*max(ni+nj-2*dot_ij,0)/((1-ni)^2+eps) + eps))
// row-normalized. N=8192, D=64. Output f32 [N,N] = 256 MB.
// exp(-acosh(1+t)) = 1/(u+sqrt(u^2-1)) = u - sqrt(t^2+2t), u=1+t  (exact identity;
// no rcp needed; s^2 computed in t-space so tiny diagonal t survives).
// Hi-only bf16 Gram: only the diagonal is sqrt-amplified and it is forced exact
// (t=EPS). Pass A: rowsums (no stores, shfl+LDS+global atomic). Pass B:
// bitwise-identical Gram recompute + normalized nontemporal store (256 MB).
// Timed window also contains harness poison fills (~275 us fixed, measured
// r4-r6: 1 GiB fill @165us + 256 MiB out fill + restores) - not controllable.

#define N 8192
#define D 64
#define EPSF 1e-8f

typedef __bf16 bf16x8 __attribute__((ext_vector_type(8)));
typedef float  f32x4  __attribute__((ext_vector_type(4)));

static __device__ __forceinline__ unsigned short f32_to_bf16_rne(float f) {
    union { float f; uint32_t u; } c; c.f = f;
    return (unsigned short)((c.u + 0x7FFFu + ((c.u >> 16) & 1u)) >> 16);
}

// ---------------- K1: f32 -> bf16 (RNE), row norms, zero rowsum ----------------
__global__ __launch_bounds__(256) void prep_kernel(
    const float* __restrict__ emb, unsigned short* __restrict__ eh,
    float* __restrict__ nrm, float* __restrict__ rowsum)
{
    int tid = blockIdx.x * 256 + threadIdx.x;     // 2048 blocks * 256 = 8192*64 exactly
    if (tid < N) rowsum[tid] = 0.0f;              // d_ws is re-poisoned each call
    int row = tid >> 6;
    int k   = tid & 63;
    float v = emb[(size_t)row * D + k];
    eh[(size_t)row * D + k] = f32_to_bf16_rne(v);
    float sq = v * v;
    #pragma unroll
    for (int m = 32; m; m >>= 1) sq += __shfl_xor(sq, m, 64);
    if (k == 0) nrm[row] = sq;
}

// ---------------- K2: hi-only bf16 Gram via MFMA + fused epilogue ----------------
// Block = 256 thr = 4 waves, block tile 128x128 (2x2 waves of 64x64).
// Wave tile 64x64 = 4x4 frags of 16x16, K=64 via 2 x mfma_f32_16x16x32_bf16.
// A/B frag: lane l holds emb[base + (l&15)][(l>>4)*8 + e], e=0..7  (16B load).
// C/D frag: col = lane&15, row = (lane>>4)*4 + reg.
// Epilogue per (cg,rg) on one f32x4 acc (low VGPR). t-space fused:
//   t = max(fma(acc, -2*rd2, fma(nj, rd2, ci)), EPS), ci = fma(ni, rd2, EPS)
//   adp = (1+t) - sqrt(fma(t,t,2t))
// STORE=false: rowsums via shfl tree -> LDS atomic -> 1 global atomic/row/block.
// STORE=true : read rowsum, nontemporal-store normalized adp.
template <bool STORE>
__global__ __launch_bounds__(256) void gemm_epi_kernel(
    const unsigned short* __restrict__ eh, const float* __restrict__ nrm,
    float* __restrict__ out, float* __restrict__ rowsum)
{
    const int lane = threadIdx.x & 63;
    const int wid  = threadIdx.x >> 6;
    const int bx = blockIdx.x & 63;
    const int by = blockIdx.x >> 6;
    const int brow = by * 128 + (wid >> 1) * 64;
    const int bcol = bx * 128 + (wid & 1) * 64;
    const int lr = lane & 15;
    const int lk = (lane >> 4) * 8;

    __shared__ float lrs[128];                    // pass-A per-block row partials
    if (!STORE) {
        if (threadIdx.x < 128) lrs[threadIdx.x] = 0.0f;
        __syncthreads();
    }

    bf16x8 ah[4][2];
    #pragma unroll
    for (int g = 0; g < 4; ++g)
        #pragma unroll
        for (int h = 0; h < 2; ++h)
            ah[g][h] = *reinterpret_cast<const bf16x8*>(eh + (size_t)(brow + g*16 + lr) * D + h*32 + lk);

    // Row constants per (rg, r): row index = brow + rg*16 + (lane>>4)*4 + r
    float rd2[4][4], ci[4][4], mi[4][4], sc[4][4];
    #pragma unroll
    for (int rg = 0; rg < 4; ++rg) {
        const int ibase = brow + rg * 16 + (lane >> 4) * 4;
        #pragma unroll
        for (int r = 0; r < 4; ++r) {
            float ni = nrm[ibase + r];
            float om = 1.0f - ni;
            rd2[rg][r] = 2.0f * __builtin_amdgcn_rcpf(om * om + EPSF);
            ci[rg][r]  = fmaf(ni, rd2[rg][r], EPSF);
            if (STORE) sc[rg][r] = __builtin_amdgcn_rcpf(rowsum[ibase + r] + EPSF);
            else       mi[rg][r] = -2.0f * rd2[rg][r];
        }
    }

    float rs[4][4];
    if (!STORE)
        #pragma unroll
        for (int rg = 0; rg < 4; ++rg)
            #pragma unroll
            for (int r = 0; r < 4; ++r) rs[rg][r] = 0.0f;

    auto body = [&](auto diag_c) {
        constexpr bool DIAG = decltype(diag_c)::value;
        #pragma unroll
        for (int cg = 0; cg < 4; ++cg) {
            bf16x8 bh[2];
            #pragma unroll
            for (int h = 0; h < 2; ++h)
                bh[h] = *reinterpret_cast<const bf16x8*>(eh + (size_t)(bcol + cg*16 + lr) * D + h*32 + lk);
            const int j = bcol + cg * 16 + lr;
            const float nj = nrm[j];
            #pragma unroll
            for (int rg = 0; rg < 4; ++rg) {
                f32x4 acc = (f32x4){0.f, 0.f, 0.f, 0.f};
                acc = __builtin_amdgcn_mfma_f32_16x16x32_bf16(ah[rg][0], bh[0], acc, 0, 0, 0);
                acc = __builtin_amdgcn_mfma_f32_16x16x32_bf16(ah[rg][1], bh[1], acc, 0, 0, 0);
                const int ibase = brow + rg * 16 + (lane >> 4) * 4;
                #pragma unroll
                for (int r = 0; r < 4; ++r) {
                    float f1 = fmaf(nj, rd2[rg][r], ci[rg][r]);
                    float t0;
                    if (STORE) t0 = fmaf(-2.0f, acc[r] * rd2[rg][r], f1);  // store-bound: VALU slack
                    else       t0 = fmaf(acc[r], mi[rg][r], f1);           // compute-bound: 1 fma
                    float t = fmaxf(t0, EPSF);
                    if (DIAG) { if (ibase + r == j) t = EPSF; }  // exact diagonal
                    float s = __builtin_amdgcn_sqrtf(fmaf(t, t, t + t));
                    float adp = (1.0f + t) - s;
                    if (STORE) {
                        __builtin_nontemporal_store(adp * sc[rg][r],
                            out + (size_t)(ibase + r) * N + j);
                    } else {
                        rs[rg][r] += adp;
                    }
                }
            }
        }
    };
    if (bx == by) body(std::true_type{});
    else          body(std::false_type{});

    if (!STORE) {
        // shfl tree over the 16 lanes sharing each row, then LDS-combine the
        // two waves that share each row, then one global atomic per row/block.
        #pragma unroll
        for (int rg = 0; rg < 4; ++rg) {
            const int rowloc = (wid >> 1) * 64 + rg * 16 + (lane >> 4) * 4;
            #pragma unroll
            for (int r = 0; r < 4; ++r) {
                float v = rs[rg][r];
                v += __shfl_xor(v, 1, 64);
                v += __shfl_xor(v, 2, 64);
                v += __shfl_xor(v, 4, 64);
                v += __shfl_xor(v, 8, 64);
                if (lr == 0) atomicAdd(&lrs[rowloc + r], v);
            }
        }
        __syncthreads();
        if (threadIdx.x < 128)
            atomicAdd(&rowsum[by * 128 + threadIdx.x], lrs[threadIdx.x]);
    }
}

extern "C" void kernel_launch(void* const* d_in, const int* in_sizes, int n_in,
                              void* d_out, int out_size, void* d_ws, size_t ws_size,
                              hipStream_t stream)
{
    const float* emb = (const float*)d_in[0];
    float* out = (float*)d_out;
    char* ws = (char*)d_ws;
    unsigned short* eh = (unsigned short*)ws;                        // 1 MiB
    float* nrm  = (float*)(ws + (size_t)N * D * 2);                  // 32 KiB
    float* rsum = nrm + N;                                           // 32 KiB

    hipLaunchKernelGGL(prep_kernel, dim3((N * D) / 256), dim3(256), 0, stream,
                       emb, eh, nrm, rsum);
    hipLaunchKernelGGL((gemm_epi_kernel<false>), dim3((N/128)*(N/128)), dim3(256), 0, stream,
                       eh, nrm, out, rsum);
    hipLaunchKernelGGL((gemm_epi_kernel<true>),  dim3((N/128)*(N/128)), dim3(256), 0, stream,
                       eh, nrm, out, rsum);
}